// Round 7
// baseline (624.112 us; speedup 1.0000x reference)
//
#include <hip/hip_runtime.h>
#include <math.h>

#define B_ 256
#define N_ 200
#define D_ 128
#define H_ 8
#define KD_ 16
#define L_ 3
#define FF_ 512
#define ROWS (B_*N_)          // 51200
#define BND (ROWS*D_)         // 6,553,600

typedef float f32x4 __attribute__((ext_vector_type(4)));
typedef _Float16 f16x4 __attribute__((ext_vector_type(4)));
typedef _Float16 f16x8 __attribute__((ext_vector_type(8)));

__device__ __forceinline__ ushort f2h_bits(float f) {
  _Float16 h = (_Float16)f;
  union { _Float16 h; ushort u; } v; v.h = h; return v.u;
}
__device__ __forceinline__ float h2f(ushort u) {
  union { ushort u; _Float16 h; } v; v.u = u; return (float)v.h;
}
// fp16 hi/lo split: hi + lo reconstructs f to ~2^-21 relative
__device__ __forceinline__ void splith(float f, ushort& hi, ushort& lo) {
  _Float16 h = (_Float16)f;
  float hf = (float)h;
  _Float16 l = (_Float16)(f - hf);
  union { _Float16 h; ushort u; } a, b; a.h = h; b.h = l;
  hi = a.u; lo = b.u;
}
// BN finalize from 400 partial sums: thread computes its own channel's scale/shift
__device__ __forceinline__ void bn_reduce(const float* psum, const float* psq,
    const float* gamma, const float* beta, int c, float& sc, float& sh) {
  if (gamma == nullptr) { sc = 1.f; sh = 0.f; return; }
  float s = 0.f, q = 0.f;
  for (int r = 0; r < 400; r++) { s += psum[r*128 + c]; q += psq[r*128 + c]; }
  const float invM = 1.f / 51200.f;
  float m = s * invM;
  float v = fmaf(q, invM, -m * m);
  float rr = rsqrtf(v + 1e-5f);
  sc = rr * gamma[c];
  sh = fmaf(-m, sc, beta[c]);
}

// ---------------- embed: h = x @ Wemb + bemb -> h hi/lo fp16 ----------------
__global__ __launch_bounds__(256) void embed_kernel(const float* __restrict__ x,
    const float* __restrict__ Wemb, const float* __restrict__ bemb,
    ushort* __restrict__ hhi, ushort* __restrict__ hlo)
{
  int i4 = blockIdx.x * 256 + threadIdx.x;   // ROWS*32 float4s
  int r  = i4 >> 5, c4 = i4 & 31;
  float x0 = x[2*r], x1 = x[2*r + 1];
  const float4 w0 = ((const float4*)Wemb)[c4];
  const float4 w1 = ((const float4*)Wemb)[32 + c4];
  const float4 bb = ((const float4*)bemb)[c4];
  float o[4];
  o[0] = fmaf(x0, w0.x, fmaf(x1, w1.x, bb.x));
  o[1] = fmaf(x0, w0.y, fmaf(x1, w1.y, bb.y));
  o[2] = fmaf(x0, w0.z, fmaf(x1, w1.z, bb.z));
  o[3] = fmaf(x0, w0.w, fmaf(x1, w1.w, bb.w));
  ushort hi[4], lo[4];
#pragma unroll
  for (int k = 0; k < 4; k++) splith(o[k], hi[k], lo[k]);
  uint2 ph, pl;
  ph.x = (uint)hi[0] | ((uint)hi[1] << 16);
  ph.y = (uint)hi[2] | ((uint)hi[3] << 16);
  pl.x = (uint)lo[0] | ((uint)lo[1] << 16);
  pl.y = (uint)lo[2] | ((uint)lo[3] << 16);
  ((uint2*)hhi)[i4] = ph;
  ((uint2*)hlo)[i4] = pl;
}

// ------------- static weight transposes (Wo, W2) -> single fp16 [N][K] -------------
__global__ __launch_bounds__(256) void t_wo(const float* __restrict__ Wo,
    ushort* __restrict__ dh)
{
  int i = blockIdx.x * 256 + threadIdx.x;     // L*128*128 = 49152 exact
  int l = i / 16384, r = i % 16384;
  int n = r >> 7, k = r & 127;
  int hh = k >> 4, kd = k & 15;
  float w = Wo[l*16384 + hh*2048 + kd*128 + n];
  dh[i] = f2h_bits(w);
}
__global__ __launch_bounds__(256) void t_w2(const float* __restrict__ W2,
    ushort* __restrict__ dh)
{
  int i = blockIdx.x * 256 + threadIdx.x;     // L*128*512 = 196608 exact
  int l = i / 65536, r = i % 65536;
  int d = r >> 9, f = r & 511;
  float w = W2[l*65536 + f*128 + d];
  dh[i] = f2h_bits(w);
}

// ------------- fold BN into QKV weights + inline BN2-finalize (gamma=null -> identity) -------
// Q rows pre-scaled by 0.25*log2(e). Block 0 publishes scale/shift for the outproj GEMM.
__global__ __launch_bounds__(128) void fold_qkv(const float* __restrict__ Wq,
    const float* __restrict__ Wk, const float* __restrict__ Wv,
    const float* __restrict__ psum, const float* __restrict__ psq,
    const float* __restrict__ gamma, const float* __restrict__ beta,
    ushort* __restrict__ wh, float* __restrict__ bout,
    float* __restrict__ scout, float* __restrict__ shout)
{
  __shared__ float wsum[2];
  int n = blockIdx.x;                     // 0..383
  int k = threadIdx.x;                    // 0..127
  float sc, sh;
  bn_reduce(psum, psq, gamma, beta, k, sc, sh);
  if (n == 0) { scout[k] = sc; shout[k] = sh; }
  int which = n >> 7, hh = (n >> 4) & 7, kd = n & 15;
  const float* src = (which == 0) ? Wq : (which == 1) ? Wk : Wv;
  float w = src[hh*2048 + k*16 + kd];
  if (which == 0) w *= 0.25f * 1.44269504088896340736f;   // fold 1/sqrt(KD)*log2(e) into Q
  wh[n*128 + k] = f2h_bits(w * sc);
  float p = sh * w;
#pragma unroll
  for (int d = 1; d < 64; d <<= 1) p += __shfl_xor(p, d);
  if ((k & 63) == 0) wsum[k >> 6] = p;
  __syncthreads();
  if (k == 0) bout[n] = wsum[0] + wsum[1];
}

// ------------- fold BN1 into W1 + inline BN1-finalize -------------
__global__ __launch_bounds__(128) void fold_w1(const float* __restrict__ W1,
    const float* __restrict__ b1,
    const float* __restrict__ psum, const float* __restrict__ psq,
    const float* __restrict__ gamma, const float* __restrict__ beta,
    ushort* __restrict__ wh, float* __restrict__ bout,
    float* __restrict__ scout, float* __restrict__ shout)
{
  __shared__ float wsum[2];
  int f = blockIdx.x;                     // 0..511
  int k = threadIdx.x;                    // 0..127
  float sc, sh;
  bn_reduce(psum, psq, gamma, beta, k, sc, sh);
  if (f == 0) { scout[k] = sc; shout[k] = sh; }
  float w = W1[k*512 + f];
  wh[f*128 + k] = f2h_bits(w * sc);
  float p = sh * w;
#pragma unroll
  for (int d = 1; d < 64; d <<= 1) p += __shfl_xor(p, d);
  if ((k & 63) == 0) wsum[k >> 6] = p;
  __syncthreads();
  if (k == 0) bout[f] = b1[f] + wsum[0] + wsum[1];
}

// ---------------- fp16 MFMA GEMM: A = hi(/lo) fp16, B = single fp16 ----------------
// ALO: A has a lo-correction array (2 MFMA/acc); else 1 MFMA/acc.
// OUTQKV: scatter to head-major [head][row][16] Q/K/V (single fp16).
// RESIDBN: residual read from hi/lo fp16 pair (may alias o0/o1 outputs -> no restrict).
// Block index: bijective XCD swizzle so blocks sharing an A-panel land on one XCD.
template<int K, bool ALO, bool BIAS, bool RELU, bool RESIDBN,
         bool OUTQKV, bool OUT16, bool OUTHL, bool STATS>
__global__ __launch_bounds__(256, 2) void gemm_mfma(
    const ushort* __restrict__ Ahi, const ushort* __restrict__ Alo,
    const ushort* __restrict__ Wh,
    const float* __restrict__ bias,
    const ushort* rhi, const ushort* rlo,
    const float* __restrict__ rsc, const float* __restrict__ rsh,
    ushort* o0, ushort* o1, ushort* o2,
    float* __restrict__ psum, float* __restrict__ psq, int Ntot)
{
  __shared__ ushort AhiS[128*64];
  __shared__ ushort AloS[ALO ? 128*64 : 8];
  __shared__ ushort BhS [128*64];
  const int t    = threadIdx.x;
  // ---- XCD-bijective block swizzle ----
  const int nx   = gridDim.x;
  const int nwg  = nx * gridDim.y;
  const int lin  = blockIdx.y * nx + blockIdx.x;
  const int q8   = nwg >> 3, r8 = nwg & 7;
  const int xcd  = lin & 7, i8 = lin >> 3;
  const int wg   = (xcd < r8 ? xcd*(q8+1) : r8*(q8+1) + (xcd-r8)*q8) + i8;
  const int bm   = (wg / nx) * 128;
  const int bn   = (wg % nx) * 128;
  const int lane = t & 63;
  const int w    = t >> 6, wm = w >> 1, wn = w & 1;
  const int quad = lane >> 4, l15 = lane & 15;
  const int bky  = wg / nx;               // for STATS partial index

  f32x4 acc[4][4];
#pragma unroll
  for (int i = 0; i < 4; i++)
#pragma unroll
    for (int j = 0; j < 4; j++) acc[i][j] = (f32x4){0.f, 0.f, 0.f, 0.f};

  const ushort* AhiB = Ahi + (size_t)bm * K;
  const ushort* AloB = ALO ? (Alo + (size_t)bm * K) : nullptr;
  const ushort* BhB  = Wh  + (size_t)bn * K;

  for (int k0 = 0; k0 < K; k0 += 64) {
#pragma unroll
    for (int i = 0; i < 4; i++) {
      int idx = i * 256 + t;
      int row = idx >> 3, c = idx & 7;
      int k8  = c ^ (row & 7);
      size_t off = (size_t)row * K + k0 + k8 * 8;
      ((uint4*)AhiS)[idx] = *(const uint4*)(AhiB + off);
      if (ALO) ((uint4*)AloS)[idx] = *(const uint4*)(AloB + off);
      ((uint4*)BhS)[idx]  = *(const uint4*)(BhB + off);
    }
    __syncthreads();
#pragma unroll
    for (int ks = 0; ks < 2; ks++) {
      f16x8 ah[4], al[4], bh[4];
#pragma unroll
      for (int i = 0; i < 4; i++) {
        int row = wm * 64 + i * 16 + l15;
        int k8  = ks * 4 + quad;
        int ci  = k8 ^ (row & 7);
        ah[i] = ((const f16x8*)AhiS)[row * 8 + ci];
        if (ALO) al[i] = ((const f16x8*)AloS)[row * 8 + ci];
        int nrow = wn * 64 + i * 16 + l15;
        int cj   = k8 ^ (nrow & 7);
        bh[i] = ((const f16x8*)BhS)[nrow * 8 + cj];
      }
#pragma unroll
      for (int i = 0; i < 4; i++)
#pragma unroll
        for (int j = 0; j < 4; j++) {
          if (ALO) acc[i][j] = __builtin_amdgcn_mfma_f32_16x16x32_f16(al[i], bh[j], acc[i][j], 0, 0, 0);
          acc[i][j] = __builtin_amdgcn_mfma_f32_16x16x32_f16(ah[i], bh[j], acc[i][j], 0, 0, 0);
        }
    }
    __syncthreads();
  }

  float bv[4], scv[4], shv[4];
#pragma unroll
  for (int j = 0; j < 4; j++) {
    int col = bn + wn*64 + j*16 + l15;
    if (BIAS)    bv[j]  = bias[col];
    if (RESIDBN) { scv[j] = rsc[col]; shv[j] = rsh[col]; }
  }
  float sj[4] = {0.f,0.f,0.f,0.f}, qj[4] = {0.f,0.f,0.f,0.f};
#pragma unroll
  for (int i = 0; i < 4; i++) {
#pragma unroll
    for (int r = 0; r < 4; r++) {
      int row = bm + wm*64 + i*16 + quad*4 + r;
#pragma unroll
      for (int j = 0; j < 4; j++) {
        int col = bn + wn*64 + j*16 + l15;
        float v = acc[i][j][r];
        if (BIAS)    v += bv[j];
        if (RELU)    v = fmaxf(v, 0.f);
        if (RESIDBN) {
          size_t ri = (size_t)row * Ntot + col;
          float rr = h2f(rhi[ri]) + h2f(rlo[ri]);
          v += fmaf(rr, scv[j], shv[j]);
        }
        if (OUTQKV) {
          if (bn == 0) {                     // Q (pre-scaled) -> head-major fp16
            o0[((size_t)(col >> 4) * ROWS + row) * 16 + (col & 15)] = f2h_bits(v);
          } else if (bn == 128) {            // K -> head-major fp16
            int c = col - 128;
            o1[((size_t)(c >> 4) * ROWS + row) * 16 + (c & 15)] = f2h_bits(v);
          } else {                           // V -> head-major single fp16
            int c = col - 256;
            o2[((size_t)(c >> 4) * ROWS + row) * 16 + (c & 15)] = f2h_bits(v);
          }
        }
        if (OUT16) o0[(size_t)row * Ntot + col] = f2h_bits(v);
        if (OUTHL) {
          ushort hi, lo; splith(v, hi, lo);
          o0[(size_t)row * Ntot + col] = hi;
          o1[(size_t)row * Ntot + col] = lo;
        }
        if (STATS) { sj[j] += v; qj[j] = fmaf(v, v, qj[j]); }
      }
    }
  }
  if (STATS) {
#pragma unroll
    for (int j = 0; j < 4; j++) {
      sj[j] += __shfl_xor(sj[j], 16); sj[j] += __shfl_xor(sj[j], 32);
      qj[j] += __shfl_xor(qj[j], 16); qj[j] += __shfl_xor(qj[j], 32);
    }
    float* ssum = (float*)AhiS;     // safe: k-loop ended with barrier
    float* ssq  = ssum + 128;
    if (t < 128) { ssum[t] = 0.f; ssq[t] = 0.f; }
    __syncthreads();
    if (quad == 0) {
#pragma unroll
      for (int j = 0; j < 4; j++) {
        int col = wn*64 + j*16 + l15;
        atomicAdd(&ssum[col], sj[j]);
        atomicAdd(&ssq[col],  qj[j]);
      }
    }
    __syncthreads();
    if (t < 128) {
      psum[bky * 128 + t] = ssum[t];
      psq [bky * 128 + t] = ssq[t];
    }
  }
}

// ---------------- MFMA fused attention (head-major dense inputs, single-fp16 V) ----------------
__global__ __launch_bounds__(256) void attn_kernel(const ushort* __restrict__ qs,
    const ushort* __restrict__ ks, const ushort* __restrict__ vh,
    ushort* __restrict__ hd)
{
  __shared__ __align__(16) _Float16 Ksh[208*24];    // [key][kd], pitch 24
  __shared__ __align__(16) _Float16 VTh[16*216];    // V^T [kd][key], pitch 216
  const int b  = blockIdx.x >> 3;
  const int hh = blockIdx.x & 7;
  const int t  = threadIdx.x;
  const size_t rb = (size_t)b * N_;
  const size_t hb = ((size_t)hh * ROWS + rb) * 16;   // element base of this (head, batch)

  // ---- stage K [208][24]: 16B loads, zero pad rows 200..207 ----
  for (int i = t; i < 208*2; i += 256) {
    int n = i >> 1, half = i & 1;
    uint4 kv = {0u, 0u, 0u, 0u};
    if (n < N_) kv = *(const uint4*)(ks + hb + n*16 + half*8);
    *(uint4*)&Ksh[n*24 + half*8] = kv;
  }
  // ---- stage V^T: 16B loads + LDS transpose scatter ----
  for (int i = t; i < 208*2; i += 256) {
    int n = i >> 1, half = i & 1;
    uint4 v0 = {0u, 0u, 0u, 0u};
    if (n < N_) v0 = *(const uint4*)(vh + hb + n*16 + half*8);
    const ushort* e0 = (const ushort*)&v0;
#pragma unroll
    for (int q = 0; q < 8; q++)
      ((ushort*)VTh)[(half*8 + q)*216 + n] = e0[q];
  }
  __syncthreads();

  const int lane = t & 63;
  const int w    = t >> 6;
  const int l15  = lane & 15;
  const int g    = lane >> 4;

  for (int qt = w; qt < 13; qt += 4) {
    int qr  = qt*16 + l15;                 // query row in [0,208)
    int qrc = qr < N_ ? qr : N_-1;         // clamp pad rows (results discarded)
    f16x4 bq = *(const f16x4*)(qs + hb + (size_t)qrc*16 + g*4);

    // S^T tiles: ct[kt] holds scores (log2-units) for keys kt*16+g*4+r, query q=l15
    f32x4 ct[13];
#pragma unroll
    for (int kt = 0; kt < 13; kt++) {
      f16x4 ak = *(const f16x4*)&Ksh[(kt*16 + l15)*24 + g*4];
      ct[kt] = __builtin_amdgcn_mfma_f32_16x16x16f16(ak, bq, (f32x4){0.f,0.f,0.f,0.f}, 0, 0, 0);
    }
    // mask pad keys (192+g*4+r >= 200)
#pragma unroll
    for (int r = 0; r < 4; r++)
      if (g*4 + r >= 8) ct[12][r] = -1e30f;

    // row max over 13 tiles then across lane groups
    float m0 = -1e30f, m1 = -1e30f;
#pragma unroll
    for (int kt = 0; kt < 13; kt++) {
      m0 = fmaxf(m0, fmaxf(ct[kt][0], ct[kt][1]));
      m1 = fmaxf(m1, fmaxf(ct[kt][2], ct[kt][3]));
    }
    float m = fmaxf(m0, m1);
    m = fmaxf(m, __shfl_xor(m, 16));
    m = fmaxf(m, __shfl_xor(m, 32));

    // exp2 + row sum
    float la0 = 0.f, la1 = 0.f, la2 = 0.f, la3 = 0.f;
#pragma unroll
    for (int kt = 0; kt < 13; kt++) {
      float p0 = __builtin_amdgcn_exp2f(ct[kt][0] - m);
      float p1 = __builtin_amdgcn_exp2f(ct[kt][1] - m);
      float p2 = __builtin_amdgcn_exp2f(ct[kt][2] - m);
      float p3 = __builtin_amdgcn_exp2f(ct[kt][3] - m);
      la0 += p0; la1 += p1; la2 += p2; la3 += p3;
      ct[kt][0] = p0; ct[kt][1] = p1; ct[kt][2] = p2; ct[kt][3] = p3;
    }
    float l = (la0 + la1) + (la2 + la3);
    l += __shfl_xor(l, 16);
    l += __shfl_xor(l, 32);

    // O^T = V^T P^T — P^T B-frags come straight from ct
    f32x4 och = {0.f,0.f,0.f,0.f};
#pragma unroll
    for (int kt = 0; kt < 13; kt++) {
      f16x4 pt = { (_Float16)ct[kt][0], (_Float16)ct[kt][1],
                   (_Float16)ct[kt][2], (_Float16)ct[kt][3] };
      f16x4 avh = *(const f16x4*)&VTh[l15*216 + kt*16 + g*4];
      och = __builtin_amdgcn_mfma_f32_16x16x16f16(avh, pt, och, 0, 0, 0);
    }

    if (qr < N_) {
      float inv = __builtin_amdgcn_rcpf(l);
      ushort o16[4];
#pragma unroll
      for (int r = 0; r < 4; r++) o16[r] = f2h_bits(och[r] * inv);
      uint2 p;
      p.x = (uint)o16[0] | ((uint)o16[1] << 16);
      p.y = (uint)o16[2] | ((uint)o16[3] << 16);
      *(uint2*)(hd + (rb + qr)*128 + hh*16 + g*4) = p;
    }
  }
}

// ---------------- final: inline BN2-finalize + apply + per-batch mean ----------------
__global__ __launch_bounds__(128) void bn_mean_final(const ushort* __restrict__ hhi,
    const ushort* __restrict__ hlo,
    const float* __restrict__ psum, const float* __restrict__ psq,
    const float* __restrict__ gamma, const float* __restrict__ beta,
    float* __restrict__ outh, float* __restrict__ mout)
{
  int b = blockIdx.x, d = threadIdx.x;
  float sc, sh;
  bn_reduce(psum, psq, gamma, beta, d, sc, sh);
  float s = 0.f;
  for (int n = 0; n < N_; n++) {
    size_t idx = ((size_t)b * N_ + n) * 128 + d;
    float v = fmaf(h2f(hhi[idx]) + h2f(hlo[idx]), sc, sh);
    outh[idx] = v;
    s += v;
  }
  mout[b * 128 + d] = s * (1.f / N_);
}

extern "C" void kernel_launch(void* const* d_in, const int* in_sizes, int n_in,
                              void* d_out, int out_size, void* d_ws, size_t ws_size,
                              hipStream_t stream)
{
  const float* x    = (const float*)d_in[0];
  const float* Wemb = (const float*)d_in[1];
  const float* bemb = (const float*)d_in[2];
  const float* Wq   = (const float*)d_in[3];
  const float* Wk   = (const float*)d_in[4];
  const float* Wv   = (const float*)d_in[5];
  const float* Wo   = (const float*)d_in[6];
  const float* bn1g = (const float*)d_in[7];
  const float* bn1b = (const float*)d_in[8];
  const float* W1   = (const float*)d_in[9];
  const float* b1   = (const float*)d_in[10];
  const float* W2   = (const float*)d_in[11];
  const float* b2   = (const float*)d_in[12];
  const float* bn2g = (const float*)d_in[13];
  const float* bn2b = (const float*)d_in[14];
  float* out = (float*)d_out;

  char* wsb = (char*)d_ws;
  ushort* h_hi  = (ushort*)wsb;                     // 13,107,200 B (fp16 hi)
  ushort* h_lo  = (ushort*)(wsb + 13107200);        // 13,107,200 B (fp16 lo)
  char*   phase = wsb + 26214400;                   // 65,536,000 B union
  ushort* qsb   = (ushort*)phase;                   //   attn: 13,107,200 B (Q head-major)
  ushort* ksb   = (ushort*)(phase + 13107200);      //   attn: 13,107,200 B (K head-major)
  ushort* vhh   = (ushort*)(phase + 26214400);      //   attn: 13,107,200 B (V fp16)
  ushort* hd    = (ushort*)(phase + 52428800);      //   attn: 13,107,200 B (heads fp16)
  ushort* hid   = (ushort*)phase;                   //   ffn: 52,428,800 B (hidden fp16)
  char*   wp    = wsb + 91750400;
  ushort* woT   = (ushort*)wp;                      // 98,304 B
  ushort* w2T   = (ushort*)(wp + 98304);            // 393,216 B
  ushort* fqkvw = (ushort*)(wp + 491520);           // 98,304 B
  ushort* fw1w  = (ushort*)(wp + 589824);           // 131,072 B
  float*  fqkv_b = (float*)(wp + 720896);           // 1,536 B
  float*  fw1_b  = (float*)(wp + 722432);           // 2,048 B
  float*  psum   = (float*)(wp + 724480);           // 204,800 B
  float*  psq    = (float*)(wp + 929280);           // 204,800 B
  float*  sc_a   = (float*)(wp + 1134080);
  float*  sh_a   = (float*)(wp + 1134592);
  float*  sc_b   = (float*)(wp + 1135104);
  float*  sh_b   = (float*)(wp + 1135616);

  embed_kernel<<<6400, 256, 0, stream>>>(x, Wemb, bemb, h_hi, h_lo);
  t_wo<<<192, 256, 0, stream>>>(Wo, woT);
  t_w2<<<768, 256, 0, stream>>>(W2, w2T);

  for (int l = 0; l < L_; l++) {
    // fold BN2(prev layer) into QKV weights (identity at l=0); publishes sc_b/sh_b
    fold_qkv<<<384, 128, 0, stream>>>(Wq + l*16384, Wk + l*16384, Wv + l*16384,
                                      psum, psq,
                                      l == 0 ? nullptr : bn2g + (l-1)*128,
                                      l == 0 ? nullptr : bn2b + (l-1)*128,
                                      fqkvw, fqkv_b, sc_b, sh_b);
    // QKV projection -> head-major Q/K/V fp16
    gemm_mfma<128, true, true, false, false, true, false, false, false>
        <<<dim3(3, 400), 256, 0, stream>>>(
        h_hi, h_lo, fqkvw, fqkv_b, nullptr, nullptr, nullptr, nullptr,
        qsb, ksb, vhh, nullptr, nullptr, 384);
    // attention -> heads fp16 [row][128]
    attn_kernel<<<B_ * H_, 256, 0, stream>>>(qsb, ksb, vhh, hd);
    // out-proj (1 MFMA/acc) + BN-folded residual (from h hi/lo) -> h hi/lo + BN1 stats
    gemm_mfma<128, false, false, false, true, false, false, true, true>
        <<<dim3(1, 400), 256, 0, stream>>>(
        hd, nullptr, woT + l*16384, nullptr, h_hi, h_lo, sc_b, sh_b,
        h_hi, h_lo, nullptr, psum, psq, 128);
    // fold BN1 into W1 (inline finalize); publishes sc_a/sh_a
    fold_w1<<<512, 128, 0, stream>>>(W1 + l*65536, b1 + l*512,
                                     psum, psq, bn1g + l*128, bn1b + l*128,
                                     fw1w, fw1_b, sc_a, sh_a);
    // FFN1 + folded bias + relu -> hidden single fp16
    gemm_mfma<128, true, true, true, false, false, true, false, false>
        <<<dim3(4, 400), 256, 0, stream>>>(
        h_hi, h_lo, fw1w, fw1_b, nullptr, nullptr, nullptr, nullptr,
        hid, nullptr, nullptr, nullptr, nullptr, 512);
    // FFN2 (1 MFMA/acc) + bias + BN1-folded residual -> h hi/lo + BN2 stats
    gemm_mfma<512, false, true, false, true, false, false, true, true>
        <<<dim3(1, 400), 256, 0, stream>>>(
        hid, nullptr, w2T + l*65536, b2 + l*128, h_hi, h_lo, sc_a, sh_a,
        h_hi, h_lo, nullptr, psum, psq, 128);
  }

  bn_mean_final<<<B_, 128, 0, stream>>>(h_hi, h_lo, psum, psq,
                                        bn2g + 2*128, bn2b + 2*128, out, out + BND);
}

// Round 8
// 596.950 us; speedup vs baseline: 1.0455x; 1.0455x over previous
//
#include <hip/hip_runtime.h>
#include <math.h>

#define B_ 256
#define N_ 200
#define D_ 128
#define H_ 8
#define KD_ 16
#define L_ 3
#define FF_ 512
#define ROWS (B_*N_)          // 51200
#define BND (ROWS*D_)         // 6,553,600

typedef float f32x4 __attribute__((ext_vector_type(4)));
typedef _Float16 f16x4 __attribute__((ext_vector_type(4)));
typedef _Float16 f16x8 __attribute__((ext_vector_type(8)));

__device__ __forceinline__ ushort f2h_bits(float f) {
  _Float16 h = (_Float16)f;
  union { _Float16 h; ushort u; } v; v.h = h; return v.u;
}
__device__ __forceinline__ float h2f(ushort u) {
  union { ushort u; _Float16 h; } v; v.u = u; return (float)v.h;
}
// fp16 hi/lo split: hi + lo reconstructs f to ~2^-21 relative
__device__ __forceinline__ void splith(float f, ushort& hi, ushort& lo) {
  _Float16 h = (_Float16)f;
  float hf = (float)h;
  _Float16 l = (_Float16)(f - hf);
  union { _Float16 h; ushort u; } a, b; a.h = h; b.h = l;
  hi = a.u; lo = b.u;
}
// BN finalize from 400 partial sums: thread computes its own channel's scale/shift
__device__ __forceinline__ void bn_reduce(const float* psum, const float* psq,
    const float* gamma, const float* beta, int c, float& sc, float& sh) {
  if (gamma == nullptr) { sc = 1.f; sh = 0.f; return; }
  float s = 0.f, q = 0.f;
  for (int r = 0; r < 400; r++) { s += psum[r*128 + c]; q += psq[r*128 + c]; }
  const float invM = 1.f / 51200.f;
  float m = s * invM;
  float v = fmaf(q, invM, -m * m);
  float rr = rsqrtf(v + 1e-5f);
  sc = rr * gamma[c];
  sh = fmaf(-m, sc, beta[c]);
}

// ---------------- embed: h = x @ Wemb + bemb -> h hi/lo fp16 ----------------
__global__ __launch_bounds__(256) void embed_kernel(const float* __restrict__ x,
    const float* __restrict__ Wemb, const float* __restrict__ bemb,
    ushort* __restrict__ hhi, ushort* __restrict__ hlo)
{
  int i4 = blockIdx.x * 256 + threadIdx.x;   // ROWS*32 float4s
  int r  = i4 >> 5, c4 = i4 & 31;
  float x0 = x[2*r], x1 = x[2*r + 1];
  const float4 w0 = ((const float4*)Wemb)[c4];
  const float4 w1 = ((const float4*)Wemb)[32 + c4];
  const float4 bb = ((const float4*)bemb)[c4];
  float o[4];
  o[0] = fmaf(x0, w0.x, fmaf(x1, w1.x, bb.x));
  o[1] = fmaf(x0, w0.y, fmaf(x1, w1.y, bb.y));
  o[2] = fmaf(x0, w0.z, fmaf(x1, w1.z, bb.z));
  o[3] = fmaf(x0, w0.w, fmaf(x1, w1.w, bb.w));
  ushort hi[4], lo[4];
#pragma unroll
  for (int k = 0; k < 4; k++) splith(o[k], hi[k], lo[k]);
  uint2 ph, pl;
  ph.x = (uint)hi[0] | ((uint)hi[1] << 16);
  ph.y = (uint)hi[2] | ((uint)hi[3] << 16);
  pl.x = (uint)lo[0] | ((uint)lo[1] << 16);
  pl.y = (uint)lo[2] | ((uint)lo[3] << 16);
  ((uint2*)hhi)[i4] = ph;
  ((uint2*)hlo)[i4] = pl;
}

// ------------- static weight transposes (Wo + W2, one launch) -> fp16 [N][K] -------------
__global__ __launch_bounds__(256) void t_weights(const float* __restrict__ Wo,
    const float* __restrict__ W2, ushort* __restrict__ woT, ushort* __restrict__ w2T)
{
  int i = blockIdx.x * 256 + threadIdx.x;     // 49152 + 196608 = 245760 exact (960 blocks)
  if (i < 49152) {
    int l = i / 16384, r = i % 16384;
    int n = r >> 7, k = r & 127;
    int hh = k >> 4, kd = k & 15;
    woT[i] = f2h_bits(Wo[l*16384 + hh*2048 + kd*128 + n]);
  } else {
    int j = i - 49152;
    int l = j / 65536, r = j % 65536;
    int d = r >> 9, f = r & 511;
    w2T[j] = f2h_bits(W2[l*65536 + f*128 + d]);
  }
}

// ------------- fold BN into QKV weights + inline BN2-finalize (gamma=null -> identity) -------
// Q rows pre-scaled by 0.25*log2(e). Block 0 publishes scale/shift for the outproj GEMM.
__global__ __launch_bounds__(128) void fold_qkv(const float* __restrict__ Wq,
    const float* __restrict__ Wk, const float* __restrict__ Wv,
    const float* __restrict__ psum, const float* __restrict__ psq,
    const float* __restrict__ gamma, const float* __restrict__ beta,
    ushort* __restrict__ wh, float* __restrict__ bout,
    float* __restrict__ scout, float* __restrict__ shout)
{
  __shared__ float wsum[2];
  int n = blockIdx.x;                     // 0..383
  int k = threadIdx.x;                    // 0..127
  float sc, sh;
  bn_reduce(psum, psq, gamma, beta, k, sc, sh);
  if (n == 0) { scout[k] = sc; shout[k] = sh; }
  int which = n >> 7, hh = (n >> 4) & 7, kd = n & 15;
  const float* src = (which == 0) ? Wq : (which == 1) ? Wk : Wv;
  float w = src[hh*2048 + k*16 + kd];
  if (which == 0) w *= 0.25f * 1.44269504088896340736f;   // fold 1/sqrt(KD)*log2(e) into Q
  wh[n*128 + k] = f2h_bits(w * sc);
  float p = sh * w;
#pragma unroll
  for (int d = 1; d < 64; d <<= 1) p += __shfl_xor(p, d);
  if ((k & 63) == 0) wsum[k >> 6] = p;
  __syncthreads();
  if (k == 0) bout[n] = wsum[0] + wsum[1];
}

// ------------- fold BN1 into W1 + inline BN1-finalize -------------
__global__ __launch_bounds__(128) void fold_w1(const float* __restrict__ W1,
    const float* __restrict__ b1,
    const float* __restrict__ psum, const float* __restrict__ psq,
    const float* __restrict__ gamma, const float* __restrict__ beta,
    ushort* __restrict__ wh, float* __restrict__ bout,
    float* __restrict__ scout, float* __restrict__ shout)
{
  __shared__ float wsum[2];
  int f = blockIdx.x;                     // 0..511
  int k = threadIdx.x;                    // 0..127
  float sc, sh;
  bn_reduce(psum, psq, gamma, beta, k, sc, sh);
  if (f == 0) { scout[k] = sc; shout[k] = sh; }
  float w = W1[k*512 + f];
  wh[f*128 + k] = f2h_bits(w * sc);
  float p = sh * w;
#pragma unroll
  for (int d = 1; d < 64; d <<= 1) p += __shfl_xor(p, d);
  if ((k & 63) == 0) wsum[k >> 6] = p;
  __syncthreads();
  if (k == 0) bout[f] = b1[f] + wsum[0] + wsum[1];
}

// ---------------- fp16 MFMA GEMM: A fp16, B fp16, 1 MFMA/acc ----------------
// OUTQKV: scatter to head-major [head][row][16] Q/K/V (single fp16).
// RESIDBN: residual read from hi/lo fp16 pair (may alias o0/o1 outputs -> no restrict).
// Block index: bijective XCD swizzle so blocks sharing an A-panel land on one XCD.
template<int K, bool BIAS, bool RELU, bool RESIDBN,
         bool OUTQKV, bool OUT16, bool OUTHL, bool STATS>
__global__ __launch_bounds__(256, 2) void gemm_mfma(
    const ushort* __restrict__ Ah,
    const ushort* __restrict__ Wh,
    const float* __restrict__ bias,
    const ushort* rhi, const ushort* rlo,
    const float* __restrict__ rsc, const float* __restrict__ rsh,
    ushort* o0, ushort* o1, ushort* o2,
    float* __restrict__ psum, float* __restrict__ psq, int Ntot)
{
  __shared__ ushort AhS[128*64];
  __shared__ ushort BhS[128*64];
  const int t    = threadIdx.x;
  // ---- XCD-bijective block swizzle ----
  const int nx   = gridDim.x;
  const int nwg  = nx * gridDim.y;
  const int lin  = blockIdx.y * nx + blockIdx.x;
  const int q8   = nwg >> 3, r8 = nwg & 7;
  const int xcd  = lin & 7, i8 = lin >> 3;
  const int wg   = (xcd < r8 ? xcd*(q8+1) : r8*(q8+1) + (xcd-r8)*q8) + i8;
  const int bm   = (wg / nx) * 128;
  const int bn   = (wg % nx) * 128;
  const int lane = t & 63;
  const int w    = t >> 6, wm = w >> 1, wn = w & 1;
  const int quad = lane >> 4, l15 = lane & 15;
  const int bky  = wg / nx;               // for STATS partial index

  f32x4 acc[4][4];
#pragma unroll
  for (int i = 0; i < 4; i++)
#pragma unroll
    for (int j = 0; j < 4; j++) acc[i][j] = (f32x4){0.f, 0.f, 0.f, 0.f};

  const ushort* AhB = Ah + (size_t)bm * K;
  const ushort* BhB = Wh + (size_t)bn * K;

  for (int k0 = 0; k0 < K; k0 += 64) {
#pragma unroll
    for (int i = 0; i < 4; i++) {
      int idx = i * 256 + t;
      int row = idx >> 3, c = idx & 7;
      int k8  = c ^ (row & 7);
      size_t off = (size_t)row * K + k0 + k8 * 8;
      ((uint4*)AhS)[idx] = *(const uint4*)(AhB + off);
      ((uint4*)BhS)[idx] = *(const uint4*)(BhB + off);
    }
    __syncthreads();
#pragma unroll
    for (int ks = 0; ks < 2; ks++) {
      f16x8 ah[4], bh[4];
#pragma unroll
      for (int i = 0; i < 4; i++) {
        int row = wm * 64 + i * 16 + l15;
        int k8  = ks * 4 + quad;
        int ci  = k8 ^ (row & 7);
        ah[i] = ((const f16x8*)AhS)[row * 8 + ci];
        int nrow = wn * 64 + i * 16 + l15;
        int cj   = k8 ^ (nrow & 7);
        bh[i] = ((const f16x8*)BhS)[nrow * 8 + cj];
      }
#pragma unroll
      for (int i = 0; i < 4; i++)
#pragma unroll
        for (int j = 0; j < 4; j++)
          acc[i][j] = __builtin_amdgcn_mfma_f32_16x16x32_f16(ah[i], bh[j], acc[i][j], 0, 0, 0);
    }
    __syncthreads();
  }

  float bv[4], scv[4], shv[4];
#pragma unroll
  for (int j = 0; j < 4; j++) {
    int col = bn + wn*64 + j*16 + l15;
    if (BIAS)    bv[j]  = bias[col];
    if (RESIDBN) { scv[j] = rsc[col]; shv[j] = rsh[col]; }
  }
  float sj[4] = {0.f,0.f,0.f,0.f}, qj[4] = {0.f,0.f,0.f,0.f};
#pragma unroll
  for (int i = 0; i < 4; i++) {
#pragma unroll
    for (int r = 0; r < 4; r++) {
      int row = bm + wm*64 + i*16 + quad*4 + r;
#pragma unroll
      for (int j = 0; j < 4; j++) {
        int col = bn + wn*64 + j*16 + l15;
        float v = acc[i][j][r];
        if (BIAS)    v += bv[j];
        if (RELU)    v = fmaxf(v, 0.f);
        if (RESIDBN) {
          size_t ri = (size_t)row * Ntot + col;
          float rr = h2f(rhi[ri]) + h2f(rlo[ri]);
          v += fmaf(rr, scv[j], shv[j]);
        }
        if (OUTQKV) {
          if (bn == 0) {                     // Q (pre-scaled) -> head-major fp16
            o0[((size_t)(col >> 4) * ROWS + row) * 16 + (col & 15)] = f2h_bits(v);
          } else if (bn == 128) {            // K -> head-major fp16
            int c = col - 128;
            o1[((size_t)(c >> 4) * ROWS + row) * 16 + (c & 15)] = f2h_bits(v);
          } else {                           // V -> head-major single fp16
            int c = col - 256;
            o2[((size_t)(c >> 4) * ROWS + row) * 16 + (c & 15)] = f2h_bits(v);
          }
        }
        if (OUT16) o0[(size_t)row * Ntot + col] = f2h_bits(v);
        if (OUTHL) {
          ushort hi, lo; splith(v, hi, lo);
          o0[(size_t)row * Ntot + col] = hi;
          o1[(size_t)row * Ntot + col] = lo;
        }
        if (STATS) { sj[j] += v; qj[j] = fmaf(v, v, qj[j]); }
      }
    }
  }
  if (STATS) {
#pragma unroll
    for (int j = 0; j < 4; j++) {
      sj[j] += __shfl_xor(sj[j], 16); sj[j] += __shfl_xor(sj[j], 32);
      qj[j] += __shfl_xor(qj[j], 16); qj[j] += __shfl_xor(qj[j], 32);
    }
    float* ssum = (float*)AhS;     // safe: k-loop ended with barrier
    float* ssq  = ssum + 128;
    if (t < 128) { ssum[t] = 0.f; ssq[t] = 0.f; }
    __syncthreads();
    if (quad == 0) {
#pragma unroll
      for (int j = 0; j < 4; j++) {
        int col = wn*64 + j*16 + l15;
        atomicAdd(&ssum[col], sj[j]);
        atomicAdd(&ssq[col],  qj[j]);
      }
    }
    __syncthreads();
    if (t < 128) {
      psum[bky * 128 + t] = ssum[t];
      psq [bky * 128 + t] = ssq[t];
    }
  }
}

// ---------------- MFMA fused attention (head-major dense inputs, single-fp16 V) ----------------
__global__ __launch_bounds__(256) void attn_kernel(const ushort* __restrict__ qs,
    const ushort* __restrict__ ks, const ushort* __restrict__ vh,
    ushort* __restrict__ hd)
{
  __shared__ __align__(16) _Float16 Ksh[208*24];    // [key][kd], pitch 24
  __shared__ __align__(16) _Float16 VTh[16*216];    // V^T [kd][key], pitch 216
  const int b  = blockIdx.x >> 3;
  const int hh = blockIdx.x & 7;
  const int t  = threadIdx.x;
  const size_t rb = (size_t)b * N_;
  const size_t hb = ((size_t)hh * ROWS + rb) * 16;   // element base of this (head, batch)

  // ---- stage K [208][24]: 16B loads, zero pad rows 200..207 ----
  for (int i = t; i < 208*2; i += 256) {
    int n = i >> 1, half = i & 1;
    uint4 kv = {0u, 0u, 0u, 0u};
    if (n < N_) kv = *(const uint4*)(ks + hb + n*16 + half*8);
    *(uint4*)&Ksh[n*24 + half*8] = kv;
  }
  // ---- stage V^T: 16B loads + LDS transpose scatter ----
  for (int i = t; i < 208*2; i += 256) {
    int n = i >> 1, half = i & 1;
    uint4 v0 = {0u, 0u, 0u, 0u};
    if (n < N_) v0 = *(const uint4*)(vh + hb + n*16 + half*8);
    const ushort* e0 = (const ushort*)&v0;
#pragma unroll
    for (int q = 0; q < 8; q++)
      ((ushort*)VTh)[(half*8 + q)*216 + n] = e0[q];
  }
  __syncthreads();

  const int lane = t & 63;
  const int w    = t >> 6;
  const int l15  = lane & 15;
  const int g    = lane >> 4;

  for (int qt = w; qt < 13; qt += 4) {
    int qr  = qt*16 + l15;                 // query row in [0,208)
    int qrc = qr < N_ ? qr : N_-1;         // clamp pad rows (results discarded)
    f16x4 bq = *(const f16x4*)(qs + hb + (size_t)qrc*16 + g*4);

    // S^T tiles: ct[kt] holds scores (log2-units) for keys kt*16+g*4+r, query q=l15
    f32x4 ct[13];
#pragma unroll
    for (int kt = 0; kt < 13; kt++) {
      f16x4 ak = *(const f16x4*)&Ksh[(kt*16 + l15)*24 + g*4];
      ct[kt] = __builtin_amdgcn_mfma_f32_16x16x16f16(ak, bq, (f32x4){0.f,0.f,0.f,0.f}, 0, 0, 0);
    }
    // mask pad keys (192+g*4+r >= 200)
#pragma unroll
    for (int r = 0; r < 4; r++)
      if (g*4 + r >= 8) ct[12][r] = -1e30f;

    // row max over 13 tiles then across lane groups
    float m0 = -1e30f, m1 = -1e30f;
#pragma unroll
    for (int kt = 0; kt < 13; kt++) {
      m0 = fmaxf(m0, fmaxf(ct[kt][0], ct[kt][1]));
      m1 = fmaxf(m1, fmaxf(ct[kt][2], ct[kt][3]));
    }
    float m = fmaxf(m0, m1);
    m = fmaxf(m, __shfl_xor(m, 16));
    m = fmaxf(m, __shfl_xor(m, 32));

    // exp2 + row sum
    float la0 = 0.f, la1 = 0.f, la2 = 0.f, la3 = 0.f;
#pragma unroll
    for (int kt = 0; kt < 13; kt++) {
      float p0 = __builtin_amdgcn_exp2f(ct[kt][0] - m);
      float p1 = __builtin_amdgcn_exp2f(ct[kt][1] - m);
      float p2 = __builtin_amdgcn_exp2f(ct[kt][2] - m);
      float p3 = __builtin_amdgcn_exp2f(ct[kt][3] - m);
      la0 += p0; la1 += p1; la2 += p2; la3 += p3;
      ct[kt][0] = p0; ct[kt][1] = p1; ct[kt][2] = p2; ct[kt][3] = p3;
    }
    float l = (la0 + la1) + (la2 + la3);
    l += __shfl_xor(l, 16);
    l += __shfl_xor(l, 32);

    // O^T = V^T P^T — P^T B-frags come straight from ct
    f32x4 och = {0.f,0.f,0.f,0.f};
#pragma unroll
    for (int kt = 0; kt < 13; kt++) {
      f16x4 pt = { (_Float16)ct[kt][0], (_Float16)ct[kt][1],
                   (_Float16)ct[kt][2], (_Float16)ct[kt][3] };
      f16x4 avh = *(const f16x4*)&VTh[l15*216 + kt*16 + g*4];
      och = __builtin_amdgcn_mfma_f32_16x16x16f16(avh, pt, och, 0, 0, 0);
    }

    if (qr < N_) {
      float inv = __builtin_amdgcn_rcpf(l);
      ushort o16[4];
#pragma unroll
      for (int r = 0; r < 4; r++) o16[r] = f2h_bits(och[r] * inv);
      uint2 p;
      p.x = (uint)o16[0] | ((uint)o16[1] << 16);
      p.y = (uint)o16[2] | ((uint)o16[3] << 16);
      *(uint2*)(hd + (rb + qr)*128 + hh*16 + g*4) = p;
    }
  }
}

// ---------------- final: inline BN2-finalize + apply + per-batch mean ----------------
__global__ __launch_bounds__(256) void bn_mean_final(const ushort* __restrict__ hhi,
    const ushort* __restrict__ hlo,
    const float* __restrict__ psum, const float* __restrict__ psq,
    const float* __restrict__ gamma, const float* __restrict__ beta,
    float* __restrict__ outh, float* __restrict__ mout)
{
  __shared__ float part[2][128];
  int b = blockIdx.x;
  int t = threadIdx.x;
  int d = t & 127, half = t >> 7;
  float sc, sh;
  bn_reduce(psum, psq, gamma, beta, d, sc, sh);
  float s = 0.f;
  for (int n = half*100; n < half*100 + 100; n++) {
    size_t idx = ((size_t)b * N_ + n) * 128 + d;
    float v = fmaf(h2f(hhi[idx]) + h2f(hlo[idx]), sc, sh);
    outh[idx] = v;
    s += v;
  }
  part[half][d] = s;
  __syncthreads();
  if (half == 0) mout[b * 128 + d] = (part[0][d] + part[1][d]) * (1.f / N_);
}

extern "C" void kernel_launch(void* const* d_in, const int* in_sizes, int n_in,
                              void* d_out, int out_size, void* d_ws, size_t ws_size,
                              hipStream_t stream)
{
  const float* x    = (const float*)d_in[0];
  const float* Wemb = (const float*)d_in[1];
  const float* bemb = (const float*)d_in[2];
  const float* Wq   = (const float*)d_in[3];
  const float* Wk   = (const float*)d_in[4];
  const float* Wv   = (const float*)d_in[5];
  const float* Wo   = (const float*)d_in[6];
  const float* bn1g = (const float*)d_in[7];
  const float* bn1b = (const float*)d_in[8];
  const float* W1   = (const float*)d_in[9];
  const float* b1   = (const float*)d_in[10];
  const float* W2   = (const float*)d_in[11];
  const float* b2   = (const float*)d_in[12];
  const float* bn2g = (const float*)d_in[13];
  const float* bn2b = (const float*)d_in[14];
  float* out = (float*)d_out;

  char* wsb = (char*)d_ws;
  ushort* h_hi  = (ushort*)wsb;                     // 13,107,200 B (fp16 hi)
  ushort* h_lo  = (ushort*)(wsb + 13107200);        // 13,107,200 B (fp16 lo)
  char*   phase = wsb + 26214400;                   // 65,536,000 B union
  ushort* qsb   = (ushort*)phase;                   //   attn: 13,107,200 B (Q head-major)
  ushort* ksb   = (ushort*)(phase + 13107200);      //   attn: 13,107,200 B (K head-major)
  ushort* vhh   = (ushort*)(phase + 26214400);      //   attn: 13,107,200 B (V fp16)
  ushort* hd    = (ushort*)(phase + 52428800);      //   attn: 13,107,200 B (heads fp16)
  ushort* hid   = (ushort*)phase;                   //   ffn: 52,428,800 B (hidden fp16)
  char*   wp    = wsb + 91750400;
  ushort* woT   = (ushort*)wp;                      // 98,304 B
  ushort* w2T   = (ushort*)(wp + 98304);            // 393,216 B
  ushort* fqkvw = (ushort*)(wp + 491520);           // 98,304 B
  ushort* fw1w  = (ushort*)(wp + 589824);           // 131,072 B
  float*  fqkv_b = (float*)(wp + 720896);           // 1,536 B
  float*  fw1_b  = (float*)(wp + 722432);           // 2,048 B
  float*  psum   = (float*)(wp + 724480);           // 204,800 B
  float*  psq    = (float*)(wp + 929280);           // 204,800 B
  float*  sc_a   = (float*)(wp + 1134080);
  float*  sh_a   = (float*)(wp + 1134592);
  float*  sc_b   = (float*)(wp + 1135104);
  float*  sh_b   = (float*)(wp + 1135616);

  embed_kernel<<<6400, 256, 0, stream>>>(x, Wemb, bemb, h_hi, h_lo);
  t_weights<<<960, 256, 0, stream>>>(Wo, W2, woT, w2T);

  for (int l = 0; l < L_; l++) {
    // fold BN2(prev layer) into QKV weights (identity at l=0); publishes sc_b/sh_b
    fold_qkv<<<384, 128, 0, stream>>>(Wq + l*16384, Wk + l*16384, Wv + l*16384,
                                      psum, psq,
                                      l == 0 ? nullptr : bn2g + (l-1)*128,
                                      l == 0 ? nullptr : bn2b + (l-1)*128,
                                      fqkvw, fqkv_b, sc_b, sh_b);
    // QKV projection (A = h_hi only) -> head-major Q/K/V fp16
    gemm_mfma<128, true, false, false, true, false, false, false>
        <<<dim3(3, 400), 256, 0, stream>>>(
        h_hi, fqkvw, fqkv_b, nullptr, nullptr, nullptr, nullptr,
        qsb, ksb, vhh, nullptr, nullptr, 384);
    // attention -> heads fp16 [row][128]
    attn_kernel<<<B_ * H_, 256, 0, stream>>>(qsb, ksb, vhh, hd);
    // out-proj + BN-folded residual (from h hi/lo) -> h hi/lo + BN1 stats
    gemm_mfma<128, false, false, true, false, false, true, true>
        <<<dim3(1, 400), 256, 0, stream>>>(
        hd, woT + l*16384, nullptr, h_hi, h_lo, sc_b, sh_b,
        h_hi, h_lo, nullptr, psum, psq, 128);
    // fold BN1 into W1 (inline finalize); publishes sc_a/sh_a
    fold_w1<<<512, 128, 0, stream>>>(W1 + l*65536, b1 + l*512,
                                     psum, psq, bn1g + l*128, bn1b + l*128,
                                     fw1w, fw1_b, sc_a, sh_a);
    // FFN1 (A = h_hi only) + folded bias + relu -> hidden single fp16
    gemm_mfma<128, true, true, false, false, true, false, false>
        <<<dim3(4, 400), 256, 0, stream>>>(
        h_hi, fw1w, fw1_b, nullptr, nullptr, nullptr, nullptr,
        hid, nullptr, nullptr, nullptr, nullptr, 512);
    // FFN2 + bias + BN1-folded residual -> h hi/lo + BN2 stats
    gemm_mfma<512, true, false, true, false, false, true, true>
        <<<dim3(1, 400), 256, 0, stream>>>(
        hid, w2T + l*65536, b2 + l*128, h_hi, h_lo, sc_a, sh_a,
        h_hi, h_lo, nullptr, psum, psq, 128);
  }

  bn_mean_final<<<B_, 256, 0, stream>>>(h_hi, h_lo, psum, psq,
                                        bn2g + 2*128, bn2b + 2*128, out, out + BND);
}

// Round 9
// 527.704 us; speedup vs baseline: 1.1827x; 1.1312x over previous
//
#include <hip/hip_runtime.h>
#include <math.h>

#define B_ 256
#define N_ 200
#define D_ 128
#define H_ 8
#define KD_ 16
#define L_ 3
#define FF_ 512
#define ROWS (B_*N_)          // 51200
#define BND (ROWS*D_)         // 6,553,600

typedef float f32x4 __attribute__((ext_vector_type(4)));
typedef _Float16 f16x4 __attribute__((ext_vector_type(4)));
typedef _Float16 f16x8 __attribute__((ext_vector_type(8)));

__device__ __forceinline__ ushort f2h_bits(float f) {
  _Float16 h = (_Float16)f;
  union { _Float16 h; ushort u; } v; v.h = h; return v.u;
}
__device__ __forceinline__ float h2f(ushort u) {
  union { ushort u; _Float16 h; } v; v.u = u; return (float)v.h;
}
// BN finalize from 128-float atomic accumulators (2 loads)
__device__ __forceinline__ void bn_reduce(const float* psum, const float* psq,
    const float* gamma, const float* beta, int c, float& sc, float& sh) {
  if (gamma == nullptr) { sc = 1.f; sh = 0.f; return; }
  float s = psum[c], q = psq[c];
  const float invM = 1.f / 51200.f;
  float m = s * invM;
  float v = fmaf(q, invM, -m * m);
  float rr = rsqrtf(v + 1e-5f);
  sc = rr * gamma[c];
  sh = fmaf(-m, sc, beta[c]);
}

// ---------------- init: embed (h fp16) + weight transposes + stat-zero, one launch ----------------
__global__ __launch_bounds__(256) void init_kernel(const float* __restrict__ x,
    const float* __restrict__ Wemb, const float* __restrict__ bemb,
    const float* __restrict__ Wo, const float* __restrict__ W2,
    ushort* __restrict__ h, ushort* __restrict__ woT, ushort* __restrict__ w2T,
    float* __restrict__ pa_s, float* __restrict__ pa_q,
    float* __restrict__ pb_s, float* __restrict__ pb_q)
{
  int blk = blockIdx.x, t = threadIdx.x;
  if (blk < 6400) {
    int i4 = blk * 256 + t;                 // ROWS*32 float4s
    int r  = i4 >> 5, c4 = i4 & 31;
    float x0 = x[2*r], x1 = x[2*r + 1];
    const float4 w0 = ((const float4*)Wemb)[c4];
    const float4 w1 = ((const float4*)Wemb)[32 + c4];
    const float4 bb = ((const float4*)bemb)[c4];
    ushort o16[4];
    o16[0] = f2h_bits(fmaf(x0, w0.x, fmaf(x1, w1.x, bb.x)));
    o16[1] = f2h_bits(fmaf(x0, w0.y, fmaf(x1, w1.y, bb.y)));
    o16[2] = f2h_bits(fmaf(x0, w0.z, fmaf(x1, w1.z, bb.z)));
    o16[3] = f2h_bits(fmaf(x0, w0.w, fmaf(x1, w1.w, bb.w)));
    uint2 p;
    p.x = (uint)o16[0] | ((uint)o16[1] << 16);
    p.y = (uint)o16[2] | ((uint)o16[3] << 16);
    ((uint2*)h)[i4] = p;
  } else if (blk < 7360) {
    int i = (blk - 6400) * 256 + t;         // 245760 exact
    if (i < 49152) {
      int l = i / 16384, r = i % 16384;
      int n = r >> 7, k = r & 127;
      int hh = k >> 4, kd = k & 15;
      woT[i] = f2h_bits(Wo[l*16384 + hh*2048 + kd*128 + n]);
    } else {
      int j = i - 49152;
      int l = j / 65536, r = j % 65536;
      int d = r >> 9, f = r & 511;
      w2T[j] = f2h_bits(W2[l*65536 + f*128 + d]);
    }
  } else {
    if (t < 128) { pa_s[t] = 0.f; pa_q[t] = 0.f; pb_s[t] = 0.f; pb_q[t] = 0.f; }
  }
}

// ------------- fold BN2(prev) into QKV weights; zero BN1 accumulators (block 1) -------------
__global__ __launch_bounds__(128) void fold_qkv(const float* __restrict__ Wq,
    const float* __restrict__ Wk, const float* __restrict__ Wv,
    const float* __restrict__ pb_s, const float* __restrict__ pb_q,
    const float* __restrict__ gamma, const float* __restrict__ beta,
    ushort* __restrict__ wh, float* __restrict__ bout,
    float* __restrict__ scout, float* __restrict__ shout,
    float* __restrict__ pa_s, float* __restrict__ pa_q)
{
  __shared__ float wsum[2];
  int n = blockIdx.x;                     // 0..383
  int k = threadIdx.x;                    // 0..127
  float sc, sh;
  bn_reduce(pb_s, pb_q, gamma, beta, k, sc, sh);
  if (n == 0) { scout[k] = sc; shout[k] = sh; }
  if (n == 1) { pa_s[k] = 0.f; pa_q[k] = 0.f; }   // zero BN1 accum before outproj
  int which = n >> 7, hh = (n >> 4) & 7, kd = n & 15;
  const float* src = (which == 0) ? Wq : (which == 1) ? Wk : Wv;
  float w = src[hh*2048 + k*16 + kd];
  if (which == 0) w *= 0.25f * 1.44269504088896340736f;   // fold 1/sqrt(KD)*log2(e) into Q
  wh[n*128 + k] = f2h_bits(w * sc);
  float p = sh * w;
#pragma unroll
  for (int d = 1; d < 64; d <<= 1) p += __shfl_xor(p, d);
  if ((k & 63) == 0) wsum[k >> 6] = p;
  __syncthreads();
  if (k == 0) bout[n] = wsum[0] + wsum[1];
}

// ------------- fold BN1 into W1 -------------
__global__ __launch_bounds__(128) void fold_w1(const float* __restrict__ W1,
    const float* __restrict__ b1,
    const float* __restrict__ pa_s, const float* __restrict__ pa_q,
    const float* __restrict__ gamma, const float* __restrict__ beta,
    ushort* __restrict__ wh, float* __restrict__ bout,
    float* __restrict__ scout, float* __restrict__ shout)
{
  __shared__ float wsum[2];
  int f = blockIdx.x;                     // 0..511
  int k = threadIdx.x;                    // 0..127
  float sc, sh;
  bn_reduce(pa_s, pa_q, gamma, beta, k, sc, sh);
  if (f == 0) { scout[k] = sc; shout[k] = sh; }
  float w = W1[k*512 + f];
  wh[f*128 + k] = f2h_bits(w * sc);
  float p = sh * w;
#pragma unroll
  for (int d = 1; d < 64; d <<= 1) p += __shfl_xor(p, d);
  if ((k & 63) == 0) wsum[k >> 6] = p;
  __syncthreads();
  if (k == 0) bout[f] = b1[f] + wsum[0] + wsum[1];
}

// ---------------- fp16 MFMA GEMM: A fp16, B fp16, 1 MFMA/acc ----------------
// OUTQKV: scatter to head-major [head][row][16] Q/K/V (single fp16).
// RESIDBN: residual read from single fp16 h (may alias o0 output -> no restrict).
// STATS: LDS-aggregate then 128 global atomicAdds into psum/psq accumulators.
// Block index: bijective XCD swizzle so blocks sharing an A-panel land on one XCD.
template<int K, bool BIAS, bool RELU, bool RESIDBN,
         bool OUTQKV, bool OUT16, bool STATS>
__global__ __launch_bounds__(256, 2) void gemm_mfma(
    const ushort* __restrict__ Ah,
    const ushort* __restrict__ Wh,
    const float* __restrict__ bias,
    const ushort* rh,
    const float* __restrict__ rsc, const float* __restrict__ rsh,
    ushort* o0, ushort* o1, ushort* o2,
    float* __restrict__ psum, float* __restrict__ psq, int Ntot)
{
  __shared__ ushort AhS[128*64];
  __shared__ ushort BhS[128*64];
  const int t    = threadIdx.x;
  // ---- XCD-bijective block swizzle ----
  const int nx   = gridDim.x;
  const int nwg  = nx * gridDim.y;
  const int lin  = blockIdx.y * nx + blockIdx.x;
  const int q8   = nwg >> 3, r8 = nwg & 7;
  const int xcd  = lin & 7, i8 = lin >> 3;
  const int wg   = (xcd < r8 ? xcd*(q8+1) : r8*(q8+1) + (xcd-r8)*q8) + i8;
  const int bm   = (wg / nx) * 128;
  const int bn   = (wg % nx) * 128;
  const int lane = t & 63;
  const int w    = t >> 6, wm = w >> 1, wn = w & 1;
  const int quad = lane >> 4, l15 = lane & 15;

  f32x4 acc[4][4];
#pragma unroll
  for (int i = 0; i < 4; i++)
#pragma unroll
    for (int j = 0; j < 4; j++) acc[i][j] = (f32x4){0.f, 0.f, 0.f, 0.f};

  const ushort* AhB = Ah + (size_t)bm * K;
  const ushort* BhB = Wh + (size_t)bn * K;

  for (int k0 = 0; k0 < K; k0 += 64) {
#pragma unroll
    for (int i = 0; i < 4; i++) {
      int idx = i * 256 + t;
      int row = idx >> 3, c = idx & 7;
      int k8  = c ^ (row & 7);
      size_t off = (size_t)row * K + k0 + k8 * 8;
      ((uint4*)AhS)[idx] = *(const uint4*)(AhB + off);
      ((uint4*)BhS)[idx] = *(const uint4*)(BhB + off);
    }
    __syncthreads();
#pragma unroll
    for (int ks = 0; ks < 2; ks++) {
      f16x8 ah[4], bh[4];
#pragma unroll
      for (int i = 0; i < 4; i++) {
        int row = wm * 64 + i * 16 + l15;
        int k8  = ks * 4 + quad;
        int ci  = k8 ^ (row & 7);
        ah[i] = ((const f16x8*)AhS)[row * 8 + ci];
        int nrow = wn * 64 + i * 16 + l15;
        int cj   = k8 ^ (nrow & 7);
        bh[i] = ((const f16x8*)BhS)[nrow * 8 + cj];
      }
#pragma unroll
      for (int i = 0; i < 4; i++)
#pragma unroll
        for (int j = 0; j < 4; j++)
          acc[i][j] = __builtin_amdgcn_mfma_f32_16x16x32_f16(ah[i], bh[j], acc[i][j], 0, 0, 0);
    }
    __syncthreads();
  }

  float bv[4], scv[4], shv[4];
#pragma unroll
  for (int j = 0; j < 4; j++) {
    int col = bn + wn*64 + j*16 + l15;
    if (BIAS)    bv[j]  = bias[col];
    if (RESIDBN) { scv[j] = rsc[col]; shv[j] = rsh[col]; }
  }
  float sj[4] = {0.f,0.f,0.f,0.f}, qj[4] = {0.f,0.f,0.f,0.f};
#pragma unroll
  for (int i = 0; i < 4; i++) {
#pragma unroll
    for (int r = 0; r < 4; r++) {
      int row = bm + wm*64 + i*16 + quad*4 + r;
#pragma unroll
      for (int j = 0; j < 4; j++) {
        int col = bn + wn*64 + j*16 + l15;
        float v = acc[i][j][r];
        if (BIAS)    v += bv[j];
        if (RELU)    v = fmaxf(v, 0.f);
        if (RESIDBN) {
          float rr = h2f(rh[(size_t)row * Ntot + col]);
          v += fmaf(rr, scv[j], shv[j]);
        }
        if (OUTQKV) {
          if (bn == 0) {                     // Q (pre-scaled) -> head-major fp16
            o0[((size_t)(col >> 4) * ROWS + row) * 16 + (col & 15)] = f2h_bits(v);
          } else if (bn == 128) {            // K -> head-major fp16
            int c = col - 128;
            o1[((size_t)(c >> 4) * ROWS + row) * 16 + (c & 15)] = f2h_bits(v);
          } else {                           // V -> head-major single fp16
            int c = col - 256;
            o2[((size_t)(c >> 4) * ROWS + row) * 16 + (c & 15)] = f2h_bits(v);
          }
        }
        if (OUT16) o0[(size_t)row * Ntot + col] = f2h_bits(v);
        if (STATS) { sj[j] += v; qj[j] = fmaf(v, v, qj[j]); }
      }
    }
  }
  if (STATS) {
#pragma unroll
    for (int j = 0; j < 4; j++) {
      sj[j] += __shfl_xor(sj[j], 16); sj[j] += __shfl_xor(sj[j], 32);
      qj[j] += __shfl_xor(qj[j], 16); qj[j] += __shfl_xor(qj[j], 32);
    }
    float* ssum = (float*)AhS;     // safe: k-loop ended with barrier
    float* ssq  = ssum + 128;
    if (t < 128) { ssum[t] = 0.f; ssq[t] = 0.f; }
    __syncthreads();
    if (quad == 0) {
#pragma unroll
      for (int j = 0; j < 4; j++) {
        int col = wn*64 + j*16 + l15;
        atomicAdd(&ssum[col], sj[j]);
        atomicAdd(&ssq[col],  qj[j]);
      }
    }
    __syncthreads();
    if (t < 128) {
      atomicAdd(&psum[t], ssum[t]);
      atomicAdd(&psq[t],  ssq[t]);
    }
  }
}

// ---------------- MFMA fused attention; block 0 zeroes BN2 accumulators ----------------
__global__ __launch_bounds__(256) void attn_kernel(const ushort* __restrict__ qs,
    const ushort* __restrict__ ks, const ushort* __restrict__ vh,
    ushort* __restrict__ hd, float* __restrict__ pb_s, float* __restrict__ pb_q)
{
  __shared__ __align__(16) _Float16 Ksh[208*24];    // [key][kd], pitch 24
  __shared__ __align__(16) _Float16 VTh[16*216];    // V^T [kd][key], pitch 216
  const int b  = blockIdx.x >> 3;
  const int hh = blockIdx.x & 7;
  const int t  = threadIdx.x;
  if (blockIdx.x == 0 && t < 128) { pb_s[t] = 0.f; pb_q[t] = 0.f; }  // zero BN2 accum before FFN2
  const size_t rb = (size_t)b * N_;
  const size_t hb = ((size_t)hh * ROWS + rb) * 16;   // element base of this (head, batch)

  // ---- stage K [208][24]: 16B loads, zero pad rows 200..207 ----
  for (int i = t; i < 208*2; i += 256) {
    int n = i >> 1, half = i & 1;
    uint4 kv = {0u, 0u, 0u, 0u};
    if (n < N_) kv = *(const uint4*)(ks + hb + n*16 + half*8);
    *(uint4*)&Ksh[n*24 + half*8] = kv;
  }
  // ---- stage V^T: 16B loads + LDS transpose scatter ----
  for (int i = t; i < 208*2; i += 256) {
    int n = i >> 1, half = i & 1;
    uint4 v0 = {0u, 0u, 0u, 0u};
    if (n < N_) v0 = *(const uint4*)(vh + hb + n*16 + half*8);
    const ushort* e0 = (const ushort*)&v0;
#pragma unroll
    for (int q = 0; q < 8; q++)
      ((ushort*)VTh)[(half*8 + q)*216 + n] = e0[q];
  }
  __syncthreads();

  const int lane = t & 63;
  const int w    = t >> 6;
  const int l15  = lane & 15;
  const int g    = lane >> 4;

  for (int qt = w; qt < 13; qt += 4) {
    int qr  = qt*16 + l15;                 // query row in [0,208)
    int qrc = qr < N_ ? qr : N_-1;         // clamp pad rows (results discarded)
    f16x4 bq = *(const f16x4*)(qs + hb + (size_t)qrc*16 + g*4);

    // S^T tiles: ct[kt] holds scores (log2-units) for keys kt*16+g*4+r, query q=l15
    f32x4 ct[13];
#pragma unroll
    for (int kt = 0; kt < 13; kt++) {
      f16x4 ak = *(const f16x4*)&Ksh[(kt*16 + l15)*24 + g*4];
      ct[kt] = __builtin_amdgcn_mfma_f32_16x16x16f16(ak, bq, (f32x4){0.f,0.f,0.f,0.f}, 0, 0, 0);
    }
    // mask pad keys (192+g*4+r >= 200)
#pragma unroll
    for (int r = 0; r < 4; r++)
      if (g*4 + r >= 8) ct[12][r] = -1e30f;

    // row max over 13 tiles then across lane groups
    float m0 = -1e30f, m1 = -1e30f;
#pragma unroll
    for (int kt = 0; kt < 13; kt++) {
      m0 = fmaxf(m0, fmaxf(ct[kt][0], ct[kt][1]));
      m1 = fmaxf(m1, fmaxf(ct[kt][2], ct[kt][3]));
    }
    float m = fmaxf(m0, m1);
    m = fmaxf(m, __shfl_xor(m, 16));
    m = fmaxf(m, __shfl_xor(m, 32));

    // exp2 + row sum
    float la0 = 0.f, la1 = 0.f, la2 = 0.f, la3 = 0.f;
#pragma unroll
    for (int kt = 0; kt < 13; kt++) {
      float p0 = __builtin_amdgcn_exp2f(ct[kt][0] - m);
      float p1 = __builtin_amdgcn_exp2f(ct[kt][1] - m);
      float p2 = __builtin_amdgcn_exp2f(ct[kt][2] - m);
      float p3 = __builtin_amdgcn_exp2f(ct[kt][3] - m);
      la0 += p0; la1 += p1; la2 += p2; la3 += p3;
      ct[kt][0] = p0; ct[kt][1] = p1; ct[kt][2] = p2; ct[kt][3] = p3;
    }
    float l = (la0 + la1) + (la2 + la3);
    l += __shfl_xor(l, 16);
    l += __shfl_xor(l, 32);

    // O^T = V^T P^T — P^T B-frags come straight from ct
    f32x4 och = {0.f,0.f,0.f,0.f};
#pragma unroll
    for (int kt = 0; kt < 13; kt++) {
      f16x4 pt = { (_Float16)ct[kt][0], (_Float16)ct[kt][1],
                   (_Float16)ct[kt][2], (_Float16)ct[kt][3] };
      f16x4 avh = *(const f16x4*)&VTh[l15*216 + kt*16 + g*4];
      och = __builtin_amdgcn_mfma_f32_16x16x16f16(avh, pt, och, 0, 0, 0);
    }

    if (qr < N_) {
      float inv = __builtin_amdgcn_rcpf(l);
      ushort o16[4];
#pragma unroll
      for (int r = 0; r < 4; r++) o16[r] = f2h_bits(och[r] * inv);
      uint2 p;
      p.x = (uint)o16[0] | ((uint)o16[1] << 16);
      p.y = (uint)o16[2] | ((uint)o16[3] << 16);
      *(uint2*)(hd + (rb + qr)*128 + hh*16 + g*4) = p;
    }
  }
}

// ---------------- final: BN2-finalize + apply + per-batch mean ----------------
__global__ __launch_bounds__(256) void bn_mean_final(const ushort* __restrict__ h,
    const float* __restrict__ pb_s, const float* __restrict__ pb_q,
    const float* __restrict__ gamma, const float* __restrict__ beta,
    float* __restrict__ outh, float* __restrict__ mout)
{
  __shared__ float part[2][128];
  int b = blockIdx.x;
  int t = threadIdx.x;
  int d = t & 127, half = t >> 7;
  float sc, sh;
  bn_reduce(pb_s, pb_q, gamma, beta, d, sc, sh);
  float s = 0.f;
  for (int n = half*100; n < half*100 + 100; n++) {
    size_t idx = ((size_t)b * N_ + n) * 128 + d;
    float v = fmaf(h2f(h[idx]), sc, sh);
    outh[idx] = v;
    s += v;
  }
  part[half][d] = s;
  __syncthreads();
  if (half == 0) mout[b * 128 + d] = (part[0][d] + part[1][d]) * (1.f / N_);
}

extern "C" void kernel_launch(void* const* d_in, const int* in_sizes, int n_in,
                              void* d_out, int out_size, void* d_ws, size_t ws_size,
                              hipStream_t stream)
{
  const float* x    = (const float*)d_in[0];
  const float* Wemb = (const float*)d_in[1];
  const float* bemb = (const float*)d_in[2];
  const float* Wq   = (const float*)d_in[3];
  const float* Wk   = (const float*)d_in[4];
  const float* Wv   = (const float*)d_in[5];
  const float* Wo   = (const float*)d_in[6];
  const float* bn1g = (const float*)d_in[7];
  const float* bn1b = (const float*)d_in[8];
  const float* W1   = (const float*)d_in[9];
  const float* b1   = (const float*)d_in[10];
  const float* W2   = (const float*)d_in[11];
  const float* b2   = (const float*)d_in[12];
  const float* bn2g = (const float*)d_in[13];
  const float* bn2b = (const float*)d_in[14];
  float* out = (float*)d_out;

  char* wsb = (char*)d_ws;
  ushort* h     = (ushort*)wsb;                     // 13,107,200 B (fp16 residual stream)
  char*   phase = wsb + 13107200;                   // 65,536,000 B union
  ushort* qsb   = (ushort*)phase;                   //   attn: 13,107,200 B (Q head-major)
  ushort* ksb   = (ushort*)(phase + 13107200);      //   attn: 13,107,200 B (K head-major)
  ushort* vhh   = (ushort*)(phase + 26214400);      //   attn: 13,107,200 B (V fp16)
  ushort* hd    = (ushort*)(phase + 52428800);      //   attn: 13,107,200 B (heads fp16)
  ushort* hid   = (ushort*)phase;                   //   ffn: 52,428,800 B (hidden fp16)
  char*   wp    = wsb + 78643200;
  ushort* woT   = (ushort*)wp;                      // 98,304 B
  ushort* w2T   = (ushort*)(wp + 98304);            // 393,216 B
  ushort* fqkvw = (ushort*)(wp + 491520);           // 98,304 B
  ushort* fw1w  = (ushort*)(wp + 589824);           // 131,072 B
  float*  fqkv_b = (float*)(wp + 720896);           // 1,536 B
  float*  fw1_b  = (float*)(wp + 722432);           // 2,048 B
  float*  pa_s   = (float*)(wp + 724480);           // 512 B (BN1 sum accum)
  float*  pa_q   = (float*)(wp + 724992);           // 512 B
  float*  pb_s   = (float*)(wp + 725504);           // 512 B (BN2 sum accum)
  float*  pb_q   = (float*)(wp + 726016);           // 512 B
  float*  sc_a   = (float*)(wp + 726528);
  float*  sh_a   = (float*)(wp + 727040);
  float*  sc_b   = (float*)(wp + 727552);
  float*  sh_b   = (float*)(wp + 728064);

  init_kernel<<<7361, 256, 0, stream>>>(x, Wemb, bemb, Wo, W2, h, woT, w2T,
                                        pa_s, pa_q, pb_s, pb_q);

  for (int l = 0; l < L_; l++) {
    // fold BN2(prev layer) into QKV weights (identity at l=0); publishes sc_b/sh_b;
    // zeroes BN1 accumulators
    fold_qkv<<<384, 128, 0, stream>>>(Wq + l*16384, Wk + l*16384, Wv + l*16384,
                                      pb_s, pb_q,
                                      l == 0 ? nullptr : bn2g + (l-1)*128,
                                      l == 0 ? nullptr : bn2b + (l-1)*128,
                                      fqkvw, fqkv_b, sc_b, sh_b, pa_s, pa_q);
    // QKV projection -> head-major Q/K/V fp16
    gemm_mfma<128, true, false, false, true, false, false>
        <<<dim3(3, 400), 256, 0, stream>>>(
        h, fqkvw, fqkv_b, nullptr, nullptr, nullptr,
        qsb, ksb, vhh, nullptr, nullptr, 384);
    // attention -> heads fp16 [row][128]; zeroes BN2 accumulators
    attn_kernel<<<B_ * H_, 256, 0, stream>>>(qsb, ksb, vhh, hd, pb_s, pb_q);
    // out-proj + BN-folded residual -> h fp16 + BN1 stats (atomic)
    gemm_mfma<128, false, false, true, false, true, true>
        <<<dim3(1, 400), 256, 0, stream>>>(
        hd, woT + l*16384, nullptr, h, sc_b, sh_b,
        h, nullptr, nullptr, pa_s, pa_q, 128);
    // fold BN1 into W1; publishes sc_a/sh_a
    fold_w1<<<512, 128, 0, stream>>>(W1 + l*65536, b1 + l*512,
                                     pa_s, pa_q, bn1g + l*128, bn1b + l*128,
                                     fw1w, fw1_b, sc_a, sh_a);
    // FFN1 + folded bias + relu -> hidden fp16
    gemm_mfma<128, true, true, false, false, true, false>
        <<<dim3(4, 400), 256, 0, stream>>>(
        h, fw1w, fw1_b, nullptr, nullptr, nullptr,
        hid, nullptr, nullptr, nullptr, nullptr, 512);
    // FFN2 + bias + BN1-folded residual -> h fp16 + BN2 stats (atomic)
    gemm_mfma<512, true, false, true, false, true, true>
        <<<dim3(1, 400), 256, 0, stream>>>(
        hid, w2T + l*65536, b2 + l*128, h, sc_a, sh_a,
        h, nullptr, nullptr, pb_s, pb_q, 128);
  }

  bn_mean_final<<<B_, 256, 0, stream>>>(h, pb_s, pb_q,
                                        bn2g + 2*128, bn2b + 2*128, out, out + BND);
}